// Round 9
// baseline (224.528 us; speedup 1.0000x reference)
//
#include <hip/hip_runtime.h>

#define BINS 10
#define NTHREADS 256
#define LOG2E 1.44269504f
#define KBIAS 1024.0f
#define TILE_ELEMS 4096                // 4096 elems per block-tile (16/thread)
#define ROUND_BYTES (NTHREADS * 16)    // 4096 B per stream per round

// ---------------------------------------------------------------------------
// GHM loss. R9 = R8 asm-pipelined core + grid backfill.
// R8 post-mortem: loads 6-8 deep in flight, yet aggregate delivery 3.2 TB/s
// with NO pipe saturated; Occupancy 52% with grid == exactly 1x resident
// capacity (2048 blocks) -> dispatch skew leaves unfillable holes; per-CU BW
// matched the copy-ubench scaled by occupancy. Fix: 8192 blocks x 4096-elem
// tiles (4x oversubscription backfills holes), each tile a straight-line
// fully-prefetched pipeline: 8 asm loads up front, vmcnt(6/4/2/0) drains.
// Core math unchanged: log2-domain staircase, bias-packed counts.
// ---------------------------------------------------------------------------

typedef float        f32x4 __attribute__((ext_vector_type(4)));
typedef unsigned int u32x4 __attribute__((ext_vector_type(4)));

__device__ __forceinline__ float wave_reduce_add(float v) {
#pragma unroll
    for (int off = 32; off > 0; off >>= 1) v += __shfl_down(v, off, 64);
    return v;
}
__device__ __forceinline__ unsigned int wave_reduce_addu(unsigned int v) {
#pragma unroll
    for (int off = 32; off > 0; off >>= 1) v += __shfl_down((int)v, off, 64);
    return v;
}

__global__ __launch_bounds__(NTHREADS, 6) void ghm_pass1(
    const float* __restrict__ pred, const int* __restrict__ target,
    float* __restrict__ g_T,            // [BINS] cumulative bce2 sums
    unsigned int* __restrict__ g_C,     // [BINS] cumulative counts (1..9 used)
    int n)
{
    float T0 = 0.f;
    float Tb[9];
#pragma unroll
    for (int b = 0; b < 9; ++b) Tb[b] = 0.f;

    const int tid    = threadIdx.x;
    const int ntiles = n / TILE_ELEMS;

    // staircase constants: log2((10-b)/b), b=1..9
#define GHM_ELEM(x_, tu_)                                                   \
    {                                                                       \
        const float z = (x_) * LOG2E;                                       \
        const float w = ((tu_) != 0u) ? z : -z;                             \
        const float E = __builtin_amdgcn_exp2f(-w);                         \
        const float bce2 = __builtin_amdgcn_logf(1.0f + E);                 \
        const float ad = bce2 + KBIAS;                                      \
        T0 += bce2;                                                         \
        Tb[0] += (w <=  3.16992500f) ? ad : 0.f;                            \
        Tb[1] += (w <=  2.0f)        ? ad : 0.f;                            \
        Tb[2] += (w <=  1.22239242f) ? ad : 0.f;                            \
        Tb[3] += (w <=  0.58496250f) ? ad : 0.f;                            \
        Tb[4] += (w <=  0.0f)        ? ad : 0.f;                            \
        Tb[5] += (w <= -0.58496250f) ? ad : 0.f;                            \
        Tb[6] += (w <= -1.22239242f) ? ad : 0.f;                            \
        Tb[7] += (w <= -2.0f)        ? ad : 0.f;                            \
        Tb[8] += (w <= -3.16992500f) ? ad : 0.f;                            \
    }

#define COMPUTE(X, Tv)                                                      \
    {                                                                       \
        GHM_ELEM((X)[0], (Tv)[0]); GHM_ELEM((X)[1], (Tv)[1]);               \
        GHM_ELEM((X)[2], (Tv)[2]); GHM_ELEM((X)[3], (Tv)[3]);               \
    }

#define ISSUE(X, Tv, off)                                                   \
    asm volatile("global_load_dwordx4 %0, %2, %3\n\t"                       \
                 "global_load_dwordx4 %1, %2, %4"                           \
                 : "=&v"(X), "=&v"(Tv)                                      \
                 : "v"(off), "s"(pred), "s"(target))

#define VWAIT(nn)                                                           \
    do { asm volatile("s_waitcnt vmcnt(" #nn ")" ::: "memory");             \
         __builtin_amdgcn_sched_barrier(0); } while (0)

    if (blockIdx.x < (unsigned)ntiles) {
        unsigned int voff = (unsigned)blockIdx.x * (TILE_ELEMS * 4u)
                          + (unsigned)tid * 16u;
        f32x4 x0, x1, x2, x3;
        u32x4 t0, t1, t2, t3;

        // Whole tile prefetched: 8 loads in flight, then drain.
        ISSUE(x0, t0, voff); voff += ROUND_BYTES;
        ISSUE(x1, t1, voff); voff += ROUND_BYTES;
        ISSUE(x2, t2, voff); voff += ROUND_BYTES;
        ISSUE(x3, t3, voff);

        VWAIT(6); COMPUTE(x0, t0);
        VWAIT(4); COMPUTE(x1, t1);
        VWAIT(2); COMPUTE(x2, t2);
        VWAIT(0); COMPUTE(x3, t3);
    }

    // Tail (n % TILE_ELEMS), last block, plain scalar loads. Empty at 2^25.
    if (blockIdx.x == gridDim.x - 1) {
        for (int i = ntiles * TILE_ELEMS + tid; i < n; i += NTHREADS) {
            const float xs = pred[i];
            const unsigned int tu = (unsigned int)target[i];
            GHM_ELEM(xs, tu);
        }
    }
#undef ISSUE
#undef VWAIT
#undef COMPUTE
#undef GHM_ELEM

    // Per-thread decode of biased accumulators (exact: sum<1024, cnt<=16).
    float        sums[BINS];
    unsigned int cnts[BINS];
    sums[0] = T0; cnts[0] = 0u;
#pragma unroll
    for (int b = 1; b < BINS; ++b) {
        const float cf = floorf(Tb[b - 1] * (1.0f / KBIAS));
        cnts[b] = (unsigned int)cf;
        sums[b] = Tb[b - 1] - KBIAS * cf;
    }

    __shared__ float        r_T[BINS];
    __shared__ unsigned int r_C[BINS];
    if (tid < BINS) { r_T[tid] = 0.f; r_C[tid] = 0u; }
    __syncthreads();

    const int lane = tid & 63;
#pragma unroll
    for (int b = 0; b < BINS; ++b) {
        const float        v = wave_reduce_add(sums[b]);
        const unsigned int c = (b > 0) ? wave_reduce_addu(cnts[b]) : 0u;
        if (lane == 0) {
            atomicAdd(&r_T[b], v);
            if (b > 0) atomicAdd(&r_C[b], c);
        }
    }
    __syncthreads();

    if (tid < BINS) {
        atomicAdd(&g_T[tid], r_T[tid]);
        atomicAdd(&g_C[tid], r_C[tid]);
    }
}

__global__ void ghm_finalize(const float* __restrict__ g_T,
                             const unsigned int* __restrict__ g_C,
                             const float* __restrict__ acc_sum,
                             float* __restrict__ out, float tot, unsigned int ntot)
{
    if (threadIdx.x == 0 && blockIdx.x == 0) {
        const float LN2 = 0.69314718056f;
        float S[BINS];
        float cntf[BINS];
#pragma unroll
        for (int b = 0; b < BINS; ++b) {
            const float        Tc = g_T[b];
            const float        Tn = (b + 1 < BINS) ? g_T[b + 1] : 0.f;
            const unsigned int Cc = (b == 0) ? ntot : g_C[b];
            const unsigned int Cn = (b + 1 < BINS) ? g_C[b + 1] : 0u;
            S[b]    = (Tc - Tn) * LN2;
            cntf[b] = (float)(Cc - Cn);
        }
        float binw[BINS];
        int nne = 0;
#pragma unroll
        for (int b = 0; b < BINS; ++b) {
            const bool ne = (cntf[b] > 0.0f);
            const float accn = ne ? (0.9f * acc_sum[b] + 0.1f * cntf[b]) : acc_sum[b];
            binw[b] = ne ? (tot / accn) : 0.0f;
            nne += ne ? 1 : 0;
        }
        const float scale = (nne > 0) ? (1.0f / (float)nne) : 1.0f;
        float res = 0.0f;
#pragma unroll
        for (int b = 0; b < BINS; ++b) res += (binw[b] * scale) * S[b];
        out[0] = res / tot;
    }
}

extern "C" void kernel_launch(void* const* d_in, const int* in_sizes, int n_in,
                              void* d_out, int out_size, void* d_ws, size_t ws_size,
                              hipStream_t stream) {
    const float* pred    = (const float*)d_in[0];
    const int*   target  = (const int*)d_in[1];
    const float* acc_sum = (const float*)d_in[2];
    float*       out     = (float*)d_out;

    const int n = in_sizes[0];
    const int ntiles = n / TILE_ELEMS;
    const int grid = (ntiles > 0) ? ntiles : 1;

    float*        g_T = (float*)d_ws;
    unsigned int* g_C = (unsigned int*)((float*)d_ws + BINS);

    hipMemsetAsync(d_ws, 0, 2 * BINS * sizeof(float), stream);

    ghm_pass1<<<grid, NTHREADS, 0, stream>>>(pred, target, g_T, g_C, n);

    const float tot = (float)(n > 1 ? n : 1);
    ghm_finalize<<<1, 64, 0, stream>>>(g_T, g_C, acc_sum, out, tot, (unsigned int)n);
}

// Round 10
// 96.646 us; speedup vs baseline: 2.3232x; 2.3232x over previous
//
#include <hip/hip_runtime.h>

#define BINS 10
#define NTHREADS 256
#define LOG2E 1.44269504f
#define KBIAS 1024.0f
#define TILE_ELEMS (NTHREADS * 64)     // 16384 elems per block-tile
#define ROUND_BYTES (NTHREADS * 16)    // 4096 B per stream per round
#define PCOLS 20                       // partials per block: 10 sums + 10 cnts

// ---------------------------------------------------------------------------
// GHM loss. R10 = R8 (asm load pipeline, counted vmcnt, log2-domain
// staircase, bias-packed counts) with the global-atomic epilogue replaced by
// per-block partial rows + a tiny reduce kernel.
// R9 falsified the occupancy theory (62% occ, 2x slower); R8's read delivery
// (268MB/84us = 3.19 TB/s) sits at the copy-ubench per-direction rate, so the
// only removable overhead left is the 2048x19 same-address atomic tail.
// ---------------------------------------------------------------------------

typedef float        f32x4 __attribute__((ext_vector_type(4)));
typedef unsigned int u32x4 __attribute__((ext_vector_type(4)));

__device__ __forceinline__ float wave_reduce_add(float v) {
#pragma unroll
    for (int off = 32; off > 0; off >>= 1) v += __shfl_down(v, off, 64);
    return v;
}
__device__ __forceinline__ unsigned int wave_reduce_addu(unsigned int v) {
#pragma unroll
    for (int off = 32; off > 0; off >>= 1) v += __shfl_down((int)v, off, 64);
    return v;
}

__global__ __launch_bounds__(NTHREADS, 6) void ghm_pass1(
    const float* __restrict__ pred, const int* __restrict__ target,
    float* __restrict__ part,           // [gridDim.x][PCOLS]
    int n)
{
    float T0 = 0.f;
    float Tb[9];
#pragma unroll
    for (int b = 0; b < 9; ++b) Tb[b] = 0.f;

    const int tid    = threadIdx.x;
    const int ntiles = n / TILE_ELEMS;

    // staircase constants: log2((10-b)/b), b=1..9
#define GHM_ELEM(x_, tu_)                                                   \
    {                                                                       \
        const float z = (x_) * LOG2E;                                       \
        const float w = ((tu_) != 0u) ? z : -z;                             \
        const float E = __builtin_amdgcn_exp2f(-w);                         \
        const float bce2 = __builtin_amdgcn_logf(1.0f + E);                 \
        const float ad = bce2 + KBIAS;                                      \
        T0 += bce2;                                                         \
        Tb[0] += (w <=  3.16992500f) ? ad : 0.f;                            \
        Tb[1] += (w <=  2.0f)        ? ad : 0.f;                            \
        Tb[2] += (w <=  1.22239242f) ? ad : 0.f;                            \
        Tb[3] += (w <=  0.58496250f) ? ad : 0.f;                            \
        Tb[4] += (w <=  0.0f)        ? ad : 0.f;                            \
        Tb[5] += (w <= -0.58496250f) ? ad : 0.f;                            \
        Tb[6] += (w <= -1.22239242f) ? ad : 0.f;                            \
        Tb[7] += (w <= -2.0f)        ? ad : 0.f;                            \
        Tb[8] += (w <= -3.16992500f) ? ad : 0.f;                            \
    }

#define COMPUTE(X, Tv)                                                      \
    {                                                                       \
        GHM_ELEM((X)[0], (Tv)[0]); GHM_ELEM((X)[1], (Tv)[1]);               \
        GHM_ELEM((X)[2], (Tv)[2]); GHM_ELEM((X)[3], (Tv)[3]);               \
    }

#define ISSUE(X, Tv, off)                                                   \
    asm volatile("global_load_dwordx4 %0, %2, %3\n\t"                       \
                 "global_load_dwordx4 %1, %2, %4"                           \
                 : "=&v"(X), "=&v"(Tv)                                      \
                 : "v"(off), "s"(pred), "s"(target))

#define VWAIT(nn)                                                           \
    do { asm volatile("s_waitcnt vmcnt(" #nn ")" ::: "memory");             \
         __builtin_amdgcn_sched_barrier(0); } while (0)

    if (blockIdx.x < (unsigned)ntiles) {
        unsigned int voff = (unsigned)blockIdx.x * (TILE_ELEMS * 4u)
                          + (unsigned)tid * 16u;
        f32x4 x0, x1, x2, x3;
        u32x4 t0, t1, t2, t3;

        // prologue: 4 rounds in flight (8 loads)
        ISSUE(x0, t0, voff); voff += ROUND_BYTES;
        ISSUE(x1, t1, voff); voff += ROUND_BYTES;
        ISSUE(x2, t2, voff); voff += ROUND_BYTES;
        ISSUE(x3, t3, voff); voff += ROUND_BYTES;

#pragma unroll 1
        for (int g = 0; g < 3; ++g) {
            VWAIT(6); COMPUTE(x0, t0); ISSUE(x0, t0, voff); voff += ROUND_BYTES;
            VWAIT(6); COMPUTE(x1, t1); ISSUE(x1, t1, voff); voff += ROUND_BYTES;
            VWAIT(6); COMPUTE(x2, t2); ISSUE(x2, t2, voff); voff += ROUND_BYTES;
            VWAIT(6); COMPUTE(x3, t3); ISSUE(x3, t3, voff); voff += ROUND_BYTES;
        }
        // epilogue: drain
        VWAIT(6); COMPUTE(x0, t0);
        VWAIT(4); COMPUTE(x1, t1);
        VWAIT(2); COMPUTE(x2, t2);
        VWAIT(0); COMPUTE(x3, t3);
    }

    // Tail (n % TILE_ELEMS), last block, plain scalar loads. Empty at 2^25.
    if (blockIdx.x == gridDim.x - 1) {
        for (int i = ntiles * TILE_ELEMS + tid; i < n; i += NTHREADS) {
            const float xs = pred[i];
            const unsigned int tu = (unsigned int)target[i];
            GHM_ELEM(xs, tu);
        }
    }
#undef ISSUE
#undef VWAIT
#undef COMPUTE
#undef GHM_ELEM

    // Per-thread decode of biased accumulators (exact: sum<1024, cnt<=64).
    float        sums[BINS];
    unsigned int cnts[BINS];
    sums[0] = T0; cnts[0] = 0u;
#pragma unroll
    for (int b = 1; b < BINS; ++b) {
        const float cf = floorf(Tb[b - 1] * (1.0f / KBIAS));
        cnts[b] = (unsigned int)cf;
        sums[b] = Tb[b - 1] - KBIAS * cf;
    }

    __shared__ float        r_T[BINS];
    __shared__ unsigned int r_C[BINS];
    if (tid < BINS) { r_T[tid] = 0.f; r_C[tid] = 0u; }
    __syncthreads();

    const int lane = tid & 63;
#pragma unroll
    for (int b = 0; b < BINS; ++b) {
        const float        v = wave_reduce_add(sums[b]);
        const unsigned int c = (b > 0) ? wave_reduce_addu(cnts[b]) : 0u;
        if (lane == 0) {
            atomicAdd(&r_T[b], v);       // LDS-only, 10/wave: negligible
            if (b > 0) atomicAdd(&r_C[b], c);
        }
    }
    __syncthreads();

    // No global atomics: one partial row per block (cols 0..9 = cumulative
    // bce2 sums, cols 10..19 = cumulative counts as float).
    if (tid < PCOLS) {
        const float v = (tid < BINS) ? r_T[tid] : (float)r_C[tid - BINS];
        part[blockIdx.x * PCOLS + tid] = v;
    }
}

// Reduce 'rows' partial rows + GHM finalize math. Single block, 256 threads.
__global__ void ghm_reduce(const float* __restrict__ part,
                           const float* __restrict__ acc_sum,
                           float* __restrict__ out, float tot,
                           unsigned int ntot, int rows)
{
    __shared__ float s[PCOLS][12];
    const int tid = threadIdx.x;
    const int c = tid % PCOLS;      // column
    const int g = tid / PCOLS;      // row-group 0..12 (12 groups active)
    if (g < 12) {
        float acc = 0.f;
        for (int r = g; r < rows; r += 12) acc += part[r * PCOLS + c];
        s[c][g] = acc;
    }
    __syncthreads();

    if (tid == 0) {
        const float LN2 = 0.69314718056f;
        float T[BINS];          // cumulative bce2 sums
        float Cc[BINS];         // cumulative counts
#pragma unroll
        for (int b = 0; b < BINS; ++b) {
            float ts = 0.f, cs = 0.f;
            for (int gg = 0; gg < 12; ++gg) { ts += s[b][gg]; cs += s[b + BINS][gg]; }
            T[b] = ts; Cc[b] = cs;
        }
        Cc[0] = (float)ntot;

        float S[BINS], cntf[BINS];
#pragma unroll
        for (int b = 0; b < BINS; ++b) {
            const float Tn = (b + 1 < BINS) ? T[b + 1]  : 0.f;
            const float Cn = (b + 1 < BINS) ? Cc[b + 1] : 0.f;
            S[b]    = (T[b] - Tn) * LN2;
            cntf[b] = Cc[b] - Cn;
        }
        float binw[BINS];
        int nne = 0;
#pragma unroll
        for (int b = 0; b < BINS; ++b) {
            const bool ne = (cntf[b] > 0.0f);
            const float accn = ne ? (0.9f * acc_sum[b] + 0.1f * cntf[b]) : acc_sum[b];
            binw[b] = ne ? (tot / accn) : 0.0f;
            nne += ne ? 1 : 0;
        }
        const float scale = (nne > 0) ? (1.0f / (float)nne) : 1.0f;
        float res = 0.0f;
#pragma unroll
        for (int b = 0; b < BINS; ++b) res += (binw[b] * scale) * S[b];
        out[0] = res / tot;
    }
}

extern "C" void kernel_launch(void* const* d_in, const int* in_sizes, int n_in,
                              void* d_out, int out_size, void* d_ws, size_t ws_size,
                              hipStream_t stream) {
    const float* pred    = (const float*)d_in[0];
    const int*   target  = (const int*)d_in[1];
    const float* acc_sum = (const float*)d_in[2];
    float*       out     = (float*)d_out;

    const int n = in_sizes[0];
    const int ntiles = n / TILE_ELEMS;
    const int grid = (ntiles > 0) ? ntiles : 1;     // 2048 for N=2^25

    float* part = (float*)d_ws;                     // [grid][PCOLS], fully
                                                    // overwritten every call

    ghm_pass1<<<grid, NTHREADS, 0, stream>>>(pred, target, part, n);

    const float tot = (float)(n > 1 ? n : 1);
    ghm_reduce<<<1, NTHREADS, 0, stream>>>(part, acc_sum, out, tot,
                                           (unsigned int)n, grid);
}

// Round 11
// 84.024 us; speedup vs baseline: 2.6722x; 1.1502x over previous
//
#include <hip/hip_runtime.h>

#define BINS 10
#define NTHREADS 256
#define LOG2E 1.44269504f
#define KBIAS 1024.0f
#define TILE_ELEMS (NTHREADS * 64)     // 16384 elems per block-tile
#define ROUND_BYTES (NTHREADS * 16)    // 4096 B per stream per round

// ---------------------------------------------------------------------------
// GHM loss. R11 = R8 restored (best measured: 84.1 us).
// Roofline argument (R1-R10): six structurally diverse kernels all pin read
// delivery at 3.2-3.35 TB/s (268 MB / ~82 us) with no pipe >35% busy and
// saturated load queues (window scaling 2->8 loads changed nothing; in-flight
// bytes >> latency-BW product). m13's 6.29 TB/s copy = read 3.15 + write
// 3.15, so ~3.3 TB/s is the demonstrated read-direction ceiling on this
// machine. Mandatory traffic = 268 MB  =>  floor ~81 us; this kernel = 84.
// R9 falsified occupancy-backfill (62% occ, 2x slower); R10 falsified the
// global-atomic-tail theory (identical pass1 with/without atomics).
// Structure: inline-asm global_load_dwordx4 pairs (AITER pattern), counted
// s_waitcnt vmcnt(6) + sched_barrier(0) (rule #18), 4 rounds in flight;
// log2-domain staircase (g>=b/10 <=> w<=log2((10-b)/b)), bias-packed counts
// (count folded into sum via +1024; per-thread decode exact: sum<1024,
// cnt<=64); wave shuffle -> LDS -> 19 global atomics per block.
// ---------------------------------------------------------------------------

typedef float        f32x4 __attribute__((ext_vector_type(4)));
typedef unsigned int u32x4 __attribute__((ext_vector_type(4)));

__device__ __forceinline__ float wave_reduce_add(float v) {
#pragma unroll
    for (int off = 32; off > 0; off >>= 1) v += __shfl_down(v, off, 64);
    return v;
}
__device__ __forceinline__ unsigned int wave_reduce_addu(unsigned int v) {
#pragma unroll
    for (int off = 32; off > 0; off >>= 1) v += __shfl_down((int)v, off, 64);
    return v;
}

__global__ __launch_bounds__(NTHREADS, 6) void ghm_pass1(
    const float* __restrict__ pred, const int* __restrict__ target,
    float* __restrict__ g_T,            // [BINS] cumulative bce2 sums
    unsigned int* __restrict__ g_C,     // [BINS] cumulative counts (1..9 used)
    int n)
{
    float T0 = 0.f;
    float Tb[9];
#pragma unroll
    for (int b = 0; b < 9; ++b) Tb[b] = 0.f;

    const int tid    = threadIdx.x;
    const int ntiles = n / TILE_ELEMS;

    // staircase constants: log2((10-b)/b), b=1..9
#define GHM_ELEM(x_, tu_)                                                   \
    {                                                                       \
        const float z = (x_) * LOG2E;                                       \
        const float w = ((tu_) != 0u) ? z : -z;                             \
        const float E = __builtin_amdgcn_exp2f(-w);                         \
        const float bce2 = __builtin_amdgcn_logf(1.0f + E);                 \
        const float ad = bce2 + KBIAS;                                      \
        T0 += bce2;                                                         \
        Tb[0] += (w <=  3.16992500f) ? ad : 0.f;                            \
        Tb[1] += (w <=  2.0f)        ? ad : 0.f;                            \
        Tb[2] += (w <=  1.22239242f) ? ad : 0.f;                            \
        Tb[3] += (w <=  0.58496250f) ? ad : 0.f;                            \
        Tb[4] += (w <=  0.0f)        ? ad : 0.f;                            \
        Tb[5] += (w <= -0.58496250f) ? ad : 0.f;                            \
        Tb[6] += (w <= -1.22239242f) ? ad : 0.f;                            \
        Tb[7] += (w <= -2.0f)        ? ad : 0.f;                            \
        Tb[8] += (w <= -3.16992500f) ? ad : 0.f;                            \
    }

#define COMPUTE(X, Tv)                                                      \
    {                                                                       \
        GHM_ELEM((X)[0], (Tv)[0]); GHM_ELEM((X)[1], (Tv)[1]);               \
        GHM_ELEM((X)[2], (Tv)[2]); GHM_ELEM((X)[3], (Tv)[3]);               \
    }

#define ISSUE(X, Tv, off)                                                   \
    asm volatile("global_load_dwordx4 %0, %2, %3\n\t"                       \
                 "global_load_dwordx4 %1, %2, %4"                           \
                 : "=&v"(X), "=&v"(Tv)                                      \
                 : "v"(off), "s"(pred), "s"(target))

#define VWAIT(nn)                                                           \
    do { asm volatile("s_waitcnt vmcnt(" #nn ")" ::: "memory");             \
         __builtin_amdgcn_sched_barrier(0); } while (0)

    if (blockIdx.x < (unsigned)ntiles) {
        unsigned int voff = (unsigned)blockIdx.x * (TILE_ELEMS * 4u)
                          + (unsigned)tid * 16u;
        f32x4 x0, x1, x2, x3;
        u32x4 t0, t1, t2, t3;

        // prologue: 4 rounds in flight (8 loads)
        ISSUE(x0, t0, voff); voff += ROUND_BYTES;
        ISSUE(x1, t1, voff); voff += ROUND_BYTES;
        ISSUE(x2, t2, voff); voff += ROUND_BYTES;
        ISSUE(x3, t3, voff); voff += ROUND_BYTES;

#pragma unroll 1
        for (int g = 0; g < 3; ++g) {
            VWAIT(6); COMPUTE(x0, t0); ISSUE(x0, t0, voff); voff += ROUND_BYTES;
            VWAIT(6); COMPUTE(x1, t1); ISSUE(x1, t1, voff); voff += ROUND_BYTES;
            VWAIT(6); COMPUTE(x2, t2); ISSUE(x2, t2, voff); voff += ROUND_BYTES;
            VWAIT(6); COMPUTE(x3, t3); ISSUE(x3, t3, voff); voff += ROUND_BYTES;
        }
        // epilogue: drain
        VWAIT(6); COMPUTE(x0, t0);
        VWAIT(4); COMPUTE(x1, t1);
        VWAIT(2); COMPUTE(x2, t2);
        VWAIT(0); COMPUTE(x3, t3);
    }

    // Tail (n % TILE_ELEMS), last block, plain scalar loads. Empty at 2^25.
    if (blockIdx.x == gridDim.x - 1) {
        for (int i = ntiles * TILE_ELEMS + tid; i < n; i += NTHREADS) {
            const float xs = pred[i];
            const unsigned int tu = (unsigned int)target[i];
            GHM_ELEM(xs, tu);
        }
    }
#undef ISSUE
#undef VWAIT
#undef COMPUTE
#undef GHM_ELEM

    // Per-thread decode of biased accumulators (exact: sum<1024, cnt<=64).
    float        sums[BINS];
    unsigned int cnts[BINS];
    sums[0] = T0; cnts[0] = 0u;
#pragma unroll
    for (int b = 1; b < BINS; ++b) {
        const float cf = floorf(Tb[b - 1] * (1.0f / KBIAS));
        cnts[b] = (unsigned int)cf;
        sums[b] = Tb[b - 1] - KBIAS * cf;
    }

    __shared__ float        r_T[BINS];
    __shared__ unsigned int r_C[BINS];
    if (tid < BINS) { r_T[tid] = 0.f; r_C[tid] = 0u; }
    __syncthreads();

    const int lane = tid & 63;
#pragma unroll
    for (int b = 0; b < BINS; ++b) {
        const float        v = wave_reduce_add(sums[b]);
        const unsigned int c = (b > 0) ? wave_reduce_addu(cnts[b]) : 0u;
        if (lane == 0) {
            atomicAdd(&r_T[b], v);
            if (b > 0) atomicAdd(&r_C[b], c);
        }
    }
    __syncthreads();

    if (tid < BINS) {
        atomicAdd(&g_T[tid], r_T[tid]);
        atomicAdd(&g_C[tid], r_C[tid]);
    }
}

__global__ void ghm_finalize(const float* __restrict__ g_T,
                             const unsigned int* __restrict__ g_C,
                             const float* __restrict__ acc_sum,
                             float* __restrict__ out, float tot, unsigned int ntot)
{
    if (threadIdx.x == 0 && blockIdx.x == 0) {
        const float LN2 = 0.69314718056f;
        float S[BINS];
        float cntf[BINS];
#pragma unroll
        for (int b = 0; b < BINS; ++b) {
            const float        Tc = g_T[b];
            const float        Tn = (b + 1 < BINS) ? g_T[b + 1] : 0.f;
            const unsigned int Cc = (b == 0) ? ntot : g_C[b];
            const unsigned int Cn = (b + 1 < BINS) ? g_C[b + 1] : 0u;
            S[b]    = (Tc - Tn) * LN2;
            cntf[b] = (float)(Cc - Cn);
        }
        float binw[BINS];
        int nne = 0;
#pragma unroll
        for (int b = 0; b < BINS; ++b) {
            const bool ne = (cntf[b] > 0.0f);
            const float accn = ne ? (0.9f * acc_sum[b] + 0.1f * cntf[b]) : acc_sum[b];
            binw[b] = ne ? (tot / accn) : 0.0f;
            nne += ne ? 1 : 0;
        }
        const float scale = (nne > 0) ? (1.0f / (float)nne) : 1.0f;
        float res = 0.0f;
#pragma unroll
        for (int b = 0; b < BINS; ++b) res += (binw[b] * scale) * S[b];
        out[0] = res / tot;
    }
}

extern "C" void kernel_launch(void* const* d_in, const int* in_sizes, int n_in,
                              void* d_out, int out_size, void* d_ws, size_t ws_size,
                              hipStream_t stream) {
    const float* pred    = (const float*)d_in[0];
    const int*   target  = (const int*)d_in[1];
    const float* acc_sum = (const float*)d_in[2];
    float*       out     = (float*)d_out;

    const int n = in_sizes[0];
    const int ntiles = n / TILE_ELEMS;
    const int grid = (ntiles > 0) ? ntiles : 1;

    float*        g_T = (float*)d_ws;
    unsigned int* g_C = (unsigned int*)((float*)d_ws + BINS);

    hipMemsetAsync(d_ws, 0, 2 * BINS * sizeof(float), stream);

    ghm_pass1<<<grid, NTHREADS, 0, stream>>>(pred, target, g_T, g_C, n);

    const float tot = (float)(n > 1 ? n : 1);
    ghm_finalize<<<1, 64, 0, stream>>>(g_T, g_C, acc_sum, out, tot, (unsigned int)n);
}